// Round 1
// 944.740 us; speedup vs baseline: 1.6270x; 1.6270x over previous
//
#include <hip/hip_runtime.h>
#include <math.h>

#define N_NODES 100000
#define N_EDGES 6400000
#define D_IN 512
#define D_HID 16

// ---- bucketed counting-sort parameters ----
#define BSHIFT 7
#define BNODES 128                                   // nodes per bucket
#define NB ((N_NODES + BNODES - 1) / BNODES)         // 782 buckets
#define P2_TILE 8192                                 // edges per block in p1/p2
#define NTILES ((N_EDGES + P2_TILE - 1) / P2_TILE)   // 782
#define CAP 9728                                     // max edges/bucket (mean 8192 + 17 sigma)

// ---------------- pass 1: bucket histogram ----------------
__global__ __launch_bounds__(256) void p1_hist(const int* __restrict__ dst,
                                               int* __restrict__ bcnt) {
    __shared__ int h[NB];
    int tid = threadIdx.x;
    for (int i = tid; i < NB; i += 256) h[i] = 0;
    __syncthreads();
    int base = blockIdx.x * P2_TILE;
#pragma unroll
    for (int k = 0; k < P2_TILE / 256; k++) {
        int e = base + k * 256 + tid;
        if (e < N_EDGES) atomicAdd(&h[dst[e] >> BSHIFT], 1);
    }
    __syncthreads();
    for (int i = tid; i < NB; i += 256) {
        int c = h[i];
        if (c) atomicAdd(&bcnt[i], c);
    }
}

// ---------------- pass 2a: scan bucket counts (1 block) ----------------
__global__ void p2_scan(const int* __restrict__ bcnt, int* __restrict__ bstart,
                        int* __restrict__ bcur) {
    __shared__ int sd[1024];
    int tid = threadIdx.x;  // 1024 threads
    int v = (tid < NB) ? bcnt[tid] : 0;
    sd[tid] = v;
    __syncthreads();
    for (int off = 1; off < 1024; off <<= 1) {
        int u = (tid >= off) ? sd[tid - off] : 0;
        __syncthreads();
        sd[tid] += u;
        __syncthreads();
    }
    if (tid < NB) {
        int ex = sd[tid] - v;
        bstart[tid] = ex;
        bcur[tid] = ex;
    }
}

// ---------------- pass 2b: aggregated multisplit scatter ----------------
// Each block: LDS count per bucket, reserve one run per bucket via a single
// global atomic, then append packed (src<<7 | local_dst) into bucket regions.
__global__ __launch_bounds__(256) void p2_scatter(const int* __restrict__ src,
                                                  const int* __restrict__ dst,
                                                  int* __restrict__ bcur,
                                                  unsigned int* __restrict__ staged) {
    __shared__ int h[NB];
    int tid = threadIdx.x;
    for (int i = tid; i < NB; i += 256) h[i] = 0;
    __syncthreads();
    int base = blockIdx.x * P2_TILE;
    // phase A: count
#pragma unroll
    for (int k = 0; k < P2_TILE / 256; k++) {
        int e = base + k * 256 + tid;
        if (e < N_EDGES) atomicAdd(&h[dst[e] >> BSHIFT], 1);
    }
    __syncthreads();
    // reserve runs; turn h into per-block cursors
    for (int i = tid; i < NB; i += 256) {
        int c = h[i];
        h[i] = c ? atomicAdd(&bcur[i], c) : 0;
    }
    __syncthreads();
    // phase B: scatter
#pragma unroll
    for (int k = 0; k < P2_TILE / 256; k++) {
        int e = base + k * 256 + tid;
        if (e < N_EDGES) {
            int d = dst[e];
            int b = d >> BSHIFT;
            int pos = atomicAdd(&h[b], 1);
            staged[pos] = ((unsigned int)src[e] << BSHIFT) | (unsigned int)(d & (BNODES - 1));
        }
    }
}

// ---------------- pass 3: per-bucket CSR build (+deg, row_start, dinv) ------
// One block per bucket. Bucket edges are buffered in LDS, so the in-place
// rewrite of ebuf (staged -> final CSR of src ids) is safe.
__global__ __launch_bounds__(256) void p3_build(int* __restrict__ ebuf,
                                                const int* __restrict__ bstart,
                                                const int* __restrict__ bcnt,
                                                int* __restrict__ row_start,
                                                int* __restrict__ deg,
                                                float* __restrict__ dinv) {
    __shared__ int buf[CAP];
    __shared__ int cnt[BNODES];
    __shared__ int cur[BNODES];
    int b = blockIdx.x;
    int tid = threadIdx.x;
    int ebase = bstart[b];
    int ecnt = bcnt[b];
    if (ecnt > CAP) ecnt = CAP;  // statistically impossible; guards LDS
    if (tid < BNODES) cnt[tid] = 0;
    __syncthreads();
    for (int i = tid; i < ecnt; i += 256) {
        int v = ebuf[ebase + i];
        buf[i] = v;
        atomicAdd(&cnt[v & (BNODES - 1)], 1);
    }
    __syncthreads();
    // exclusive scan over cnt[128]
    int c = 0;
    if (tid < BNODES) {
        c = cnt[tid];
        cur[tid] = c;
    }
    __syncthreads();
    for (int off = 1; off < BNODES; off <<= 1) {
        int u = 0;
        if (tid < BNODES && tid >= off) u = cur[tid - off];
        __syncthreads();
        if (tid < BNODES) cur[tid] += u;
        __syncthreads();
    }
    int excl = 0;
    if (tid < BNODES) excl = cur[tid] - c;
    // per-node outputs
    int node = b * BNODES + tid;
    if (tid < BNODES && node < N_NODES) {
        row_start[node] = ebase + excl;
        deg[node] = c;
        dinv[node] = rsqrtf((float)c + 1.0f);  // +1 self-loop
    }
    __syncthreads();
    if (tid < BNODES) cur[tid] = excl;  // local cursor
    __syncthreads();
    for (int i = tid; i < ecnt; i += 256) {
        int v = buf[i];
        int pos = atomicAdd(&cur[v & (BNODES - 1)], 1);
        ebuf[ebase + pos] = v >> BSHIFT;  // final CSR: src id
    }
}

// ---------------- GEMM1: h1 = x @ W1  [100000x512]@[512x16] ----------------
__global__ __launch_bounds__(256) void gemm1(const float* __restrict__ x,
                                             const float* __restrict__ W1,
                                             float* __restrict__ h1) {
    __shared__ float xs[256 * 33];
    int tid = threadIdx.x;
    int row0 = blockIdx.x * 256;
    int row = row0 + tid;
    float acc[16];
#pragma unroll
    for (int c = 0; c < 16; c++) acc[c] = 0.f;

    for (int k0 = 0; k0 < D_IN; k0 += 32) {
        __syncthreads();
#pragma unroll
        for (int l = 0; l < 8; l++) {
            int idx = tid + l * 256;   // 0..2047
            int r = idx >> 3;          // row within block
            int f4 = idx & 7;          // float4 within 32-wide k tile
            int gr = row0 + r;
            float4 v = make_float4(0.f, 0.f, 0.f, 0.f);
            if (gr < N_NODES)
                v = *(const float4*)(x + (size_t)gr * D_IN + k0 + f4 * 4);
            int a = r * 33 + f4 * 4;
            xs[a] = v.x; xs[a + 1] = v.y; xs[a + 2] = v.z; xs[a + 3] = v.w;
        }
        __syncthreads();
#pragma unroll
        for (int kk = 0; kk < 32; kk++) {
            float xv = xs[tid * 33 + kk];
            const float* wr = W1 + (k0 + kk) * 16;  // wave-uniform -> s_load
#pragma unroll
            for (int c = 0; c < 16; c++) acc[c] = fmaf(xv, wr[c], acc[c]);
        }
    }
    if (row < N_NODES) {
        float4* o = (float4*)(h1 + (size_t)row * 16);
        o[0] = make_float4(acc[0], acc[1], acc[2], acc[3]);
        o[1] = make_float4(acc[4], acc[5], acc[6], acc[7]);
        o[2] = make_float4(acc[8], acc[9], acc[10], acc[11]);
        o[3] = make_float4(acc[12], acc[13], acc[14], acc[15]);
    }
}

// ---------------- Agg layer 1 (pull) + bias + ReLU + @W2 fused ----------------
__global__ __launch_bounds__(256) void agg1(const float* __restrict__ h1,
                                            const float* __restrict__ dinv,
                                            const int* __restrict__ row_start,
                                            const int* __restrict__ deg,
                                            const int* __restrict__ csr,
                                            const float* __restrict__ b1,
                                            const float* __restrict__ W2,
                                            float* __restrict__ h3) {
    int tid = threadIdx.x;
    int node = blockIdx.x * 16 + (tid >> 4);
    int c = tid & 15;
    if (node >= N_NODES) return;
    float di = dinv[node];
    float acc = h1[(size_t)node * 16 + c] * di * di;  // self-loop
    int start = row_start[node];
    int cnt = deg[node];
    int sN = 0; float vN = 0.f, dN = 0.f;
    if (cnt > 0) {
        sN = csr[start];
        vN = h1[(size_t)sN * 16 + c];
        dN = dinv[sN];
    }
    for (int t = 0; t < cnt; t++) {
        float vC = vN, dC = dN;
        if (t + 1 < cnt) {
            int s = csr[start + t + 1];
            vN = h1[(size_t)s * 16 + c];
            dN = dinv[s];
        }
        acc = fmaf(vC, dC * di, acc);
    }
    float v = acc + b1[c];
    v = v > 0.f ? v : 0.f;
    // out_row = v_row @ W2 (16x16) via in-wave broadcast
    float out = 0.f;
#pragma unroll
    for (int j = 0; j < 16; j++) {
        float vj = __shfl(v, j, 16);
        out = fmaf(vj, W2[j * 16 + c], out);
    }
    h3[(size_t)node * 16 + c] = out;
}

// ---------------- Agg layer 2 (pull) + bias + log_softmax ----------------
__global__ __launch_bounds__(256) void agg2(const float* __restrict__ h3,
                                            const float* __restrict__ dinv,
                                            const int* __restrict__ row_start,
                                            const int* __restrict__ deg,
                                            const int* __restrict__ csr,
                                            const float* __restrict__ b2,
                                            float* __restrict__ out) {
    int tid = threadIdx.x;
    int node = blockIdx.x * 16 + (tid >> 4);
    int c = tid & 15;
    if (node >= N_NODES) return;
    float di = dinv[node];
    float acc = h3[(size_t)node * 16 + c] * di * di;
    int start = row_start[node];
    int cnt = deg[node];
    int sN = 0; float vN = 0.f, dN = 0.f;
    if (cnt > 0) {
        sN = csr[start];
        vN = h3[(size_t)sN * 16 + c];
        dN = dinv[sN];
    }
    for (int t = 0; t < cnt; t++) {
        float vC = vN, dC = dN;
        if (t + 1 < cnt) {
            int s = csr[start + t + 1];
            vN = h3[(size_t)s * 16 + c];
            dN = dinv[s];
        }
        acc = fmaf(vC, dC * di, acc);
    }
    float logit = acc + b2[c];
    // log_softmax over the 16 lanes of this node
    float m = logit;
#pragma unroll
    for (int mask = 1; mask < 16; mask <<= 1)
        m = fmaxf(m, __shfl_xor(m, mask, 16));
    float e = expf(logit - m);
    float ssum = e;
#pragma unroll
    for (int mask = 1; mask < 16; mask <<= 1)
        ssum += __shfl_xor(ssum, mask, 16);
    out[(size_t)node * 16 + c] = (logit - m) - logf(ssum);
}

extern "C" void kernel_launch(void* const* d_in, const int* in_sizes, int n_in,
                              void* d_out, int out_size, void* d_ws, size_t ws_size,
                              hipStream_t stream) {
    const float* x  = (const float*)d_in[0];
    const float* W1 = (const float*)d_in[1];
    const float* b1 = (const float*)d_in[2];
    const float* W2 = (const float*)d_in[3];
    const float* b2 = (const float*)d_in[4];
    const int*   ei = (const int*)d_in[5];
    const int* src = ei;
    const int* dst = ei + N_EDGES;
    float* out = (float*)d_out;

    // workspace layout (elements, all 4B):
    int* deg       = (int*)d_ws;                  // 100096
    int* row_start = deg + 100096;                // 100096
    float* dinv    = (float*)(row_start + 100096);// 100096
    int* bcnt      = (int*)(dinv + 100096);       // 1024
    int* bstart    = bcnt + 1024;                 // 1024
    int* bcur      = bstart + 1024;               // 1024
    int* ebuf      = bcur + 1024;                 // 6400000 (staged, then CSR)
    float* h1      = (float*)(ebuf + N_EDGES);    // 1600000
    float* h3      = h1 + 1600000;                // 1600000

    hipMemsetAsync(bcnt, 0, NB * sizeof(int), stream);
    p1_hist<<<NTILES, 256, 0, stream>>>(dst, bcnt);
    p2_scan<<<1, 1024, 0, stream>>>(bcnt, bstart, bcur);
    p2_scatter<<<NTILES, 256, 0, stream>>>(src, dst, bcur, (unsigned int*)ebuf);
    p3_build<<<NB, 256, 0, stream>>>(ebuf, bstart, bcnt, row_start, deg, dinv);
    gemm1<<<(N_NODES + 255) / 256, 256, 0, stream>>>(x, W1, h1);
    agg1<<<(N_NODES + 15) / 16, 256, 0, stream>>>(h1, dinv, row_start, deg, ebuf, b1, W2, h3);
    agg2<<<(N_NODES + 15) / 16, 256, 0, stream>>>(h3, dinv, row_start, deg, ebuf, b2, out);
}